// Round 10
// baseline (2248.842 us; speedup 1.0000x reference)
//
#include <hip/hip_runtime.h>

// R17: R16 + the missing block barrier. R16's absmax failure was a cross-wave
// LDS race: epilogue staging (stw = smem + w*4288, spans smem[0..34304)) was
// written without waiting for other waves to finish their main loops, which
// still read their P' buffers (pw = smem + w*1088, spans smem[0..8704)) -
// fast wave's stw overwrote slow waves' live pw. Fix: one __syncthreads()
// between main loop and epilogue. Main loop remains completely barrier-free
// (the experiment's subject: 8 independent wave pipelines, direct global->reg
// K/V fragment loads, no LDS ring). Everything else identical to R16.

typedef short s8v __attribute__((ext_vector_type(8)));   // 8 bf16 = 4 VGPRs
typedef float f4v __attribute__((ext_vector_type(4)));
typedef unsigned short us;
typedef us us4v __attribute__((ext_vector_type(4)));

__device__ inline us f2b(float f) {  // fp32 -> bf16 RNE
  union { float f; unsigned u; } v; v.f = f;
  unsigned r = v.u + 0x7FFFu + ((v.u >> 16) & 1u);
  return (us)(r >> 16);
}

// async global->LDS, 16 B per lane; LDS dest = wave-uniform base + lane*16.
__device__ inline void gld16(const us* g, us* l) {
  __builtin_amdgcn_global_load_lds(
      (const __attribute__((address_space(1))) void*)g,
      (__attribute__((address_space(3))) void*)l, 16, 0, 0);
}

// ---------------------------------------------------------------------------
// Fused attention: O[zh] = softmax(alpha * Q K^T) V, KV-tile = 64 rows.
// Q,K: [zh][S][E] bf16. Vt: [zh][E][S] bf16 (V^T). O: [b][S][HC*E] bf16.
// Block: 512 thr / 8 waves, 128 q-rows; wave w owns rows [q0+16w, q0+16w+16).
// Per wave per tile: 64 direct K-frag loads + 64 MFMA (QK^T, accS 16x64),
// exp->P' via wave-private LDS->pa, 64 direct V-frag loads + 64 MFMA (PV,
// accO 16x512). No block barriers in the main loop: waves are independent
// pipelines. One __syncthreads() before the epilogue (stw/pw overlap).
// ---------------------------------------------------------------------------
__global__ __launch_bounds__(512, 2) void attn_fused(
    const us* __restrict__ Q, const us* __restrict__ Kh,
    const us* __restrict__ Vt, us* __restrict__ O,
    int Lh, float alpha) {
  constexpr int S = 2048, E = 512;
  // smem: main loop uses only Ps (wave-private 16x68 us at w*1088);
  // epilogue (after barrier) reuses as wave-private O staging (16x268/wave).
  __shared__ __align__(16) us smem[34304];  // 68,608 B
  const int t = threadIdx.x, w = t >> 6, ln = t & 63;
  const int m16 = ln & 15, quad = ln >> 4;

  // XCD swizzle: grid (16 qt, BHC zh). Remap so each XCD owns consecutive
  // nid = all qt of a few zh -> K/V stream shared within the XCD.
  const int gx = gridDim.x;  // 16
  const int nblk = gx * gridDim.y;
  const int flat = blockIdx.x + gx * blockIdx.y;
  int nid = flat;
  if ((nblk & 7) == 0) nid = (flat & 7) * (nblk >> 3) + (flat >> 3);
  const int qt = nid % gx, zh = nid / gx;

  const long long zoff = (long long)zh * S * E;
  const us* Qz = Q + zoff;
  const int q0 = qt * 128;

  // Resident Q fragments: lane ln holds Q[q0+16w+(ln&15)][kq*32+(ln>>4)*8 ..+7]
  s8v Qf[16];
  {
    const us* qrow = Qz + (long long)(q0 + 16 * w + m16) * E + quad * 8;
#pragma unroll
    for (int kq = 0; kq < 16; ++kq) Qf[kq] = *(const s8v*)(qrow + kq * 32);
  }

  // Per-lane fragment base pointers (row = m16 within each 16-row block).
  const us* Krow = Kh + zoff + (long long)m16 * E + quad * 8;
  const us* Vrow = Vt + zoff + (long long)m16 * S + quad * 8;

  f4v accO[4][8];
#pragma unroll
  for (int e = 0; e < 4; ++e)
#pragma unroll
    for (int nb = 0; nb < 8; ++nb) accO[e][nb] = (f4v){0.f, 0.f, 0.f, 0.f};
  float la[4] = {0.f, 0.f, 0.f, 0.f};

  us* pw = smem + w * 1088;  // wave-private P' buffer, 16 x 68 us

  for (int tau = 0; tau < S / 64; ++tau) {
    const int kv0 = tau * 64;
    // ---- QK^T: accS[nb] = Q(16 rows) . K(kv0+nb*16..+15)^T over K=512.
    f4v accS[4];
#pragma unroll
    for (int nb = 0; nb < 4; ++nb) accS[nb] = (f4v){0.f, 0.f, 0.f, 0.f};
#pragma unroll
    for (int ks = 0; ks < 16; ++ks) {
      s8v kf[4];
#pragma unroll
      for (int nb = 0; nb < 4; ++nb)
        kf[nb] = *(const s8v*)(Krow + (long long)(kv0 + nb * 16) * E + ks * 32);
#pragma unroll
      for (int nb = 0; nb < 4; ++nb)
        accS[nb] = __builtin_amdgcn_mfma_f32_16x16x32_bf16(
            Qf[ks], kf[nb], accS[nb], 0, 0, 0);
    }
    // ---- softmax-lite: P' = exp(alpha*S - 4); wave-private through Ps.
#pragma unroll
    for (int nb = 0; nb < 4; ++nb)
#pragma unroll
      for (int gg = 0; gg < 4; ++gg) {
        accS[nb][gg] = __expf(fmaf(accS[nb][gg], alpha, -4.f));
        pw[(quad * 4 + gg) * 68 + nb * 16 + m16] = f2b(accS[nb][gg]);
      }
#pragma unroll
    for (int gg = 0; gg < 4; ++gg) {  // row sums over this tile's 64 kv cols
      float s = accS[0][gg] + accS[1][gg] + accS[2][gg] + accS[3][gg];
      s += __shfl_xor(s, 1, 64);
      s += __shfl_xor(s, 2, 64);
      s += __shfl_xor(s, 4, 64);
      s += __shfl_xor(s, 8, 64);
      la[gg] += s;
    }
    asm volatile("s_waitcnt lgkmcnt(0)" ::: "memory");  // Ps writes done
    __builtin_amdgcn_sched_barrier(0);
    s8v pa0 = *(const s8v*)&pw[m16 * 68 + quad * 8];
    s8v pa1 = *(const s8v*)&pw[m16 * 68 + 32 + quad * 8];
    // ---- PV: accO[cb>>3][cb&7] += P'(16x64) . V^T(cb*16..+15 rows, kv slice)
#pragma unroll
    for (int cb4 = 0; cb4 < 8; ++cb4) {
      s8v vf[8];
#pragma unroll
      for (int j = 0; j < 4; ++j) {
        const int cb = cb4 * 4 + j;
        vf[j * 2]     = *(const s8v*)(Vrow + (long long)(cb * 16) * S + kv0);
        vf[j * 2 + 1] = *(const s8v*)(Vrow + (long long)(cb * 16) * S + kv0 + 32);
      }
#pragma unroll
      for (int j = 0; j < 4; ++j) {
        const int cb = cb4 * 4 + j;
        accO[cb >> 3][cb & 7] = __builtin_amdgcn_mfma_f32_16x16x32_bf16(
            pa0, vf[j * 2], accO[cb >> 3][cb & 7], 0, 0, 0);
        accO[cb >> 3][cb & 7] = __builtin_amdgcn_mfma_f32_16x16x32_bf16(
            pa1, vf[j * 2 + 1], accO[cb >> 3][cb & 7], 0, 0, 0);
      }
    }
  }

  // All waves' pw reads must complete before epilogue staging overwrites
  // the shared region (stw of wave w overlaps pw of waves 4w..4w+3).
  __syncthreads();

  // Epilogue: O = accO / l via wave-private LDS staging -> 512B-contiguous
  // stores.
  float inv[4];
#pragma unroll
  for (int gg = 0; gg < 4; ++gg) inv[gg] = 1.f / la[gg];
  const int b = zh >> Lh, hc = zh & ((1 << Lh) - 1);
  const int HCE = E << Lh;
  us* Ob = O + (long long)b * S * HCE + (long long)hc * E;
  us* stw = smem + w * 4288;  // wave-private 16 x 268 us
#pragma unroll
  for (int half = 0; half < 2; ++half) {
#pragma unroll
    for (int ec = 0; ec < 2; ++ec) {
      const int ecg = half * 2 + ec;
#pragma unroll
      for (int nb = 0; nb < 8; ++nb)
#pragma unroll
        for (int gg = 0; gg < 4; ++gg)
          stw[(quad * 4 + gg) * 268 + ec * 128 + nb * 16 + m16] =
              f2b(accO[ecg][nb][gg] * inv[gg]);
    }
    asm volatile("s_waitcnt lgkmcnt(0)" ::: "memory");
    __builtin_amdgcn_sched_barrier(0);
    // 32 lanes x 16B = 512B contiguous per row; 2 rows per instruction.
#pragma unroll
    for (int rp = 0; rp < 8; ++rp) {
      const int row = rp * 2 + (ln >> 5);
      const s8v v = *(const s8v*)&stw[row * 268 + (ln & 31) * 8];
      *(s8v*)&Ob[(long long)(q0 + 16 * w + row) * HCE + half * 256 +
                 (ln & 31) * 8] = v;
    }
    if (half == 0) {
      asm volatile("s_waitcnt lgkmcnt(0)" ::: "memory");  // reads done before
      __builtin_amdgcn_sched_barrier(0);                  // half-1 overwrites
    }
  }
}

// NT GEMM core: 256(M) x 256(N) tile, 8 waves (2 row-groups x 4 col-groups);
// A[M,K] (lda), B[N,K] (ldb). z = (zo<<L)|zi -> operand offsets zo*s?0+zi*s?1.
// EPI 3: merged QKV epilogue (sections q/k straight+bias, v transposed+bias).
// EPI 5: fp32 atomicAdd into Cv (split-K out-projection).
template <int EPI>
__global__ __launch_bounds__(512, 2) void gemm_nt(
    const us* __restrict__ A, int lda, long long sA0, long long sA1,
    const us* __restrict__ Bm, int ldb, long long sB0, long long sB1,
    const float* __restrict__ bias, const float* __restrict__ bias2,
    const float* __restrict__ bias3,
    void* __restrict__ Cv, void* __restrict__ C2, void* __restrict__ C3,
    int ldc, long long sC0, long long sC1,
    int K, float alpha, int L, int sbits) {
  __shared__ __align__(16) us As[2][16384];
  __shared__ __align__(16) us Bs[2][16384];
  const int t = threadIdx.x;
  const int wv = t >> 6, ln = t & 63;
  const int m16 = ln & 15, quad = ln >> 4;

  const int gx = gridDim.x, gxy = gx * gridDim.y;
  const int nblk = gxy * gridDim.z;
  const int flat = blockIdx.x + gx * blockIdx.y + gxy * blockIdx.z;
  int nid = flat;
  if ((nblk & 7) == 0) nid = (flat & 7) * (nblk >> 3) + (flat >> 3);
  const int bz = nid / gxy, rem = nid % gxy;
  const int by = rem / gx, bx = rem % gx;

  const long long row0 = (long long)by * 256;
  const long long col0 = (long long)bx * 256;
  const int zo = bz >> L, zi = bz & ((1 << L) - 1);
  const us* Az = A + zo * sA0 + zi * sA1;
  const us* Bz = Bm + zo * sB0 + zi * sB1;

  int offA[4], offB[4];
#pragma unroll
  for (int j = 0; j < 4; ++j) {
    const int c = t + 512 * j;
    const int s = c >> 6, l = c & 63;
    const int mb = s >> 1, ks = s & 1, qd = (l >> 4) & 3, mm = l & 15;
    offA[j] = (int)((row0 + mb * 16 + mm) * (long long)lda + ks * 32 + qd * 8);
    offB[j] = (int)((col0 + mb * 16 + mm) * (long long)ldb + ks * 32 + qd * 8);
  }

  f4v acc[8][4];
#pragma unroll
  for (int r = 0; r < 8; ++r)
#pragma unroll
    for (int c = 0; c < 4; ++c) acc[r][c] = (f4v){0.f, 0.f, 0.f, 0.f};

  const int nk = K >> 6;
  const int wr = wv >> 2, wc = wv & 3;

#define BARR __builtin_amdgcn_s_barrier()
#define LGKM0                                              \
  do {                                                     \
    asm volatile("s_waitcnt lgkmcnt(0)" ::: "memory");     \
    __builtin_amdgcn_sched_barrier(0);                     \
  } while (0)
#define READ_A(p_)                                                           \
  _Pragma("unroll") for (int rr = 0; rr < 2; ++rr)                           \
  _Pragma("unroll") for (int ks = 0; ks < 2; ++ks)                           \
      af[rr * 2 + ks] = *(const s8v*)&As[b]                                  \
          [(((wr * 8 + (p_) * 2 + rr) * 2 + ks) * 64 + ln) * 8];
#define MFMA_Q(p_)                                                           \
  __builtin_amdgcn_s_setprio(1);                                             \
  _Pragma("unroll") for (int ks = 0; ks < 2; ++ks)                           \
  _Pragma("unroll") for (int rr = 0; rr < 2; ++rr)                           \
  _Pragma("unroll") for (int c = 0; c < 4; ++c)                              \
      acc[(p_) * 2 + rr][c] = __builtin_amdgcn_mfma_f32_16x16x32_bf16(       \
          af[rr * 2 + ks], bfr[c * 2 + ks], acc[(p_) * 2 + rr][c], 0, 0, 0); \
  __builtin_amdgcn_s_setprio(0);

#pragma unroll
  for (int j = 0; j < 4; ++j) gld16(Az + offA[j], (us*)As[0] + (t + 512 * j) * 8);
#pragma unroll
  for (int j = 0; j < 4; ++j) gld16(Bz + offB[j], (us*)Bs[0] + (t + 512 * j) * 8);
  if (nk > 1) {
#pragma unroll
    for (int j = 0; j < 4; ++j)
      gld16(Bz + offB[j] + 64, (us*)Bs[1] + (t + 512 * j) * 8);
    gld16(Az + offA[0] + 64, (us*)As[1] + t * 8);
    gld16(Az + offA[2] + 64, (us*)As[1] + (t + 1024) * 8);
    asm volatile("s_waitcnt vmcnt(6)" ::: "memory");
  } else {
    asm volatile("s_waitcnt vmcnt(0)" ::: "memory");
  }
  BARR;

  for (int kt = 0; kt < nk; ++kt) {
    const int b = kt & 1;
    s8v bfr[8], af[4];
#pragma unroll
    for (int c = 0; c < 4; ++c)
#pragma unroll
      for (int ks = 0; ks < 2; ++ks)
        bfr[c * 2 + ks] =
            *(const s8v*)&Bs[b][(((wc * 4 + c) * 2 + ks) * 64 + ln) * 8];
    READ_A(0);
    if (kt + 1 < nk) {
      const int kof = (kt + 1) << 6;
      gld16(Az + offA[1] + kof, (us*)As[b ^ 1] + (t + 512) * 8);
      gld16(Az + offA[3] + kof, (us*)As[b ^ 1] + (t + 1536) * 8);
    }
    asm volatile("s_waitcnt lgkmcnt(8)" ::: "memory");
    BARR; LGKM0; MFMA_Q(0); BARR;
    READ_A(1);
    if (kt + 2 < nk) {
      const int kof = (kt + 2) << 6;
#pragma unroll
      for (int j = 0; j < 4; ++j)
        gld16(Bz + offB[j] + kof, (us*)Bs[b] + (t + 512 * j) * 8);
    }
    BARR; LGKM0; MFMA_Q(1); BARR;
    READ_A(2);
    if (kt + 2 < nk) {
      const int kof = (kt + 2) << 6;
      gld16(Az + offA[0] + kof, (us*)As[b] + t * 8);
      gld16(Az + offA[2] + kof, (us*)As[b] + (t + 1024) * 8);
    }
    BARR; LGKM0; MFMA_Q(2); BARR;
    READ_A(3);
    BARR; LGKM0; MFMA_Q(3);
    if (kt + 2 < nk) asm volatile("s_waitcnt vmcnt(6)" ::: "memory");
    else             asm volatile("s_waitcnt vmcnt(0)" ::: "memory");
    BARR;
  }
#undef READ_A
#undef MFMA_Q
#undef BARR
#undef LGKM0

  // Epilogue. C/D layout: col = lane&15, row = quad*4 + reg (m89-verified).
#pragma unroll
  for (int r = 0; r < 8; ++r) {
    const int inRow = wr * 128 + r * 16 + quad * 4;
    const long long gr0 = row0 + inRow;
#pragma unroll
    for (int c = 0; c < 4; ++c) {
      const long long gc = col0 + wc * 64 + c * 16 + m16;
      if (EPI == 3) {
        const int which = (int)(gc >> sbits);
        const int gsec = (int)gc & ((1 << sbits) - 1);
        const int hc = gsec >> 9, e = (int)gc & 511;
        const long long slice =
            ((long long)zo * (1 << (sbits - 9)) + hc) * 1048576LL;  // S*E
        if (which == 0) {
          us* C = (us*)Cv;
          const float bb = bias[gsec];
#pragma unroll
          for (int g = 0; g < 4; ++g)
            C[slice + (gr0 + g) * 512 + e] = f2b(acc[r][c][g] + bb);
        } else if (which == 1) {
          us* C = (us*)C2;
          const float bb = bias2[gsec];
#pragma unroll
          for (int g = 0; g < 4; ++g)
            C[slice + (gr0 + g) * 512 + e] = f2b(acc[r][c][g] + bb);
        } else {
          us* C = (us*)C3;
          const float bb = bias3[gsec];
          us4v pk;
#pragma unroll
          for (int g = 0; g < 4; ++g) pk[g] = f2b(acc[r][c][g] + bb);
          *(us4v*)&C[slice + (long long)e * 2048 + gr0] = pk;  // e*S + s
        }
      } else {  // EPI 5: split-K atomic accumulate (fp32)
        float* C = (float*)Cv + zo * sC0;
        float* p = C + gr0 * ldc + gc;
#pragma unroll
        for (int g = 0; g < 4; ++g)
          atomicAdd(&p[(long long)g * ldc], acc[r][c][g] * alpha);
      }
    }
  }
}

__global__ __launch_bounds__(256) void conv_bf16(const float* __restrict__ in,
                                                 us* __restrict__ out, int n4) {
  const int i = blockIdx.x * 256 + threadIdx.x;
  if (i < n4) {
    const float4 f = ((const float4*)in)[i];
    us4v o;
    o[0] = f2b(f.x); o[1] = f2b(f.y); o[2] = f2b(f.z); o[3] = f2b(f.w);
    ((us4v*)out)[i] = o;
  }
}

// in [Z][R][C] fp32 -> bf16 transposed [C][R], z-routed:
// dst = out + (z>>Lc)*sChunk + (z&mask)*(R*C)
__global__ __launch_bounds__(256) void conv_transpose(const float* __restrict__ in,
                                                      us* __restrict__ out,
                                                      int R, int C, int Lc,
                                                      int mask, long long sChunk) {
  __shared__ float tile[32][33];
  const int tx = threadIdx.x & 31, ty = threadIdx.x >> 5;
  const int z = blockIdx.z;
  const long long zi = (long long)z * R * C;
  us* dst = out + (long long)(z >> Lc) * sChunk + (long long)(z & mask) * R * C;
  const int r0 = blockIdx.y * 32, c0 = blockIdx.x * 32;
#pragma unroll
  for (int j = 0; j < 4; ++j)
    tile[ty + 8 * j][tx] = in[zi + (long long)(r0 + ty + 8 * j) * C + c0 + tx];
  __syncthreads();
#pragma unroll
  for (int j = 0; j < 4; ++j)
    dst[(long long)(c0 + ty + 8 * j) * R + r0 + tx] = f2b(tile[tx][ty + 8 * j]);
}

// out[b,s,:] = bp[:]
__global__ __launch_bounds__(256) void init_out_kernel(float* __restrict__ out,
                                                       const float* __restrict__ bp,
                                                       int total) {
  const int i = blockIdx.x * 256 + threadIdx.x;
  if (i < total) out[i] = bp[i & 511];  // D=512
}

extern "C" void kernel_launch(void* const* d_in, const int* in_sizes, int n_in,
                              void* d_out, int out_size, void* d_ws, size_t ws_size,
                              hipStream_t stream) {
  constexpr int Bb = 4, S = 2048, D = 512, H = 8, E = 512, HE = 4096;
  const float* x  = (const float*)d_in[0];
  const float* Wq = (const float*)d_in[1];
  const float* bq = (const float*)d_in[2];
  const float* Wk = (const float*)d_in[3];
  const float* bk = (const float*)d_in[4];
  const float* Wv = (const float*)d_in[5];
  const float* bv = (const float*)d_in[6];
  const float* Wp = (const float*)d_in[7];
  const float* bp = (const float*)d_in[8];
  float* out = (float*)d_out;

  const long long SE = (long long)S * E;
  const long long SD = (long long)S * D, ED = (long long)E * D;

  // Fixed region: xh + packed QKV weights W3 + WpT (25.2 MB).
  us* xh  = (us*)d_ws;            // B*S*D          4,194,304
  us* W3  = xh + 4194304;         // [chunk][3][HC*E][D]  6,291,456 total
  us* WpT = W3 + 6291456;         // [D][HE]        2,097,152
  us* dyn = WpT + 2097152;

  // No sc buffer: need = fixed + 4 buffers (q,k,vT,oh) per chunk.
  const size_t fixedB = (size_t)(4194304 + 6291456 + 2097152) * 2;
  int HC = 8;
  while (HC > 1) {
    const size_t need = fixedB + (size_t)4 * HC * Bb * SE * 2;
    if (need <= ws_size) break;
    HC >>= 1;
  }
  const int Lh = (HC == 8) ? 3 : (HC == 4) ? 2 : (HC == 2) ? 1 : 0;
  const int BHC = Bb * HC;
  const int sbits = 9 + Lh;  // QKV section size = HC*512 cols

  us* qh = dyn;                       // [b*HC+hc][S][E]
  us* kh = qh + (size_t)BHC * SE;
  us* vT = kh + (size_t)BHC * SE;     // [b*HC+hc][E][S]
  us* oh = vT + (size_t)BHC * SE;     // [b][S][HC][E]

  const dim3 tb(256), tg(512);
  init_out_kernel<<<dim3((Bb * S * D + 255) / 256), tb, 0, stream>>>(
      out, bp, Bb * S * D);
  conv_bf16<<<dim3(4194304 / 4 / 256), tb, 0, stream>>>(x, xh, 4194304 / 4);
  const long long sChunk = 3LL * HC * ED;  // per-chunk W3 stride
  conv_transpose<<<dim3(16, 16, H), tb, 0, stream>>>(Wq, W3, D, E, Lh, HC - 1, sChunk);
  conv_transpose<<<dim3(16, 16, H), tb, 0, stream>>>(Wk, W3 + HC * ED, D, E, Lh, HC - 1, sChunk);
  conv_transpose<<<dim3(16, 16, H), tb, 0, stream>>>(Wv, W3 + 2 * HC * ED, D, E, Lh, HC - 1, sChunk);
  conv_transpose<<<dim3(16, 128, 1), tb, 0, stream>>>(Wp, WpT, HE, D, 0, 0, 0);

  const float aS = 0.044194173824159216f;  // 1/sqrt(512)
  const dim3 gQKV(3 * HC * E / 256, 8, Bb);  // 256-col tiles; S/256 = 8 rows
  const dim3 gAT(S / 128, BHC);              // fused attn: (128-row q-tile, zh)
  const dim3 gOP(2, 8, BHC);                 // split-K: z = (b, j)

  for (int c = 0; c < H / HC; ++c) {
    const int h0 = c * HC;
    // Merged QKV projection: [S,D] @ [3*HC*E, D]^T; epilogue routes sections.
    gemm_nt<3><<<gQKV, tg, 0, stream>>>(
        xh, D, SD, 0, W3 + c * sChunk, D, 0, 0,
        bq + h0 * E, bk + h0 * E, bv + h0 * E,
        qh, kh, vT, 512, 0, SE, D, 1.f, 0, sbits);
    // Fused attention: oh[b][s][hc][e] = softmax(aS * Q K^T) V
    attn_fused<<<gAT, tg, 0, stream>>>(qh, kh, vT, oh, Lh, aS);
    // out += O @ Wp-chunk, split-K: z=(b, j), K=512 per split, atomicAdd.
    gemm_nt<5><<<gOP, tg, 0, stream>>>(
        oh, HC * E, (long long)S * HC * E, 512,
        WpT + (long long)h0 * E, HE, 0, 512,
        nullptr, nullptr, nullptr, out, nullptr, nullptr,
        D, SD, 0, 512, 1.f, Lh, 0);
  }
}

// Round 11
// 935.106 us; speedup vs baseline: 2.4049x; 2.4049x over previous
//
#include <hip/hip_runtime.h>

// R18 = R10 restored (best measured: 935.3 us). Eight structural levers were
// tested after R10 — schedule variants (R9), L3 working-set (R11), flash
// fusion (R12), coalesced epilogue (R13), NT stores + ring depth (R14),
// 2-blocks/CU (R15), barrier-free direct-load (R16/R17) — all regressed or
// neutral; every dispatch pins at ~1.25 TB/s effective memory rate
// regardless of in-kernel schedule. R10: 8-phase pipelined GEMM core
// (staging interleaved into phases, counted vmcnt(6) once per K-tile,
// lgkmcnt(8) partial drain, setprio around 16-MFMA clusters), fragment-
// linear LDS (0 bank conflicts), merged QKV, fused exp/row-sum scores
// epilogue, PV scale-by-1/l, split-K out-projection.

typedef short s8v __attribute__((ext_vector_type(8)));   // 8 bf16 = 4 VGPRs
typedef float f4v __attribute__((ext_vector_type(4)));
typedef unsigned short us;
typedef us us4v __attribute__((ext_vector_type(4)));

__device__ inline us f2b(float f) {  // fp32 -> bf16 RNE
  union { float f; unsigned u; } v; v.f = f;
  unsigned r = v.u + 0x7FFFu + ((v.u >> 16) & 1u);
  return (us)(r >> 16);
}

// async global->LDS, 16 B per lane; LDS dest = wave-uniform base + lane*16.
__device__ inline void gld16(const us* g, us* l) {
  __builtin_amdgcn_global_load_lds(
      (const __attribute__((address_space(1))) void*)g,
      (__attribute__((address_space(3))) void*)l, 16, 0, 0);
}

// NT GEMM core: 256(M) x 256(N) tile, 8 waves (2 row-groups x 4 col-groups);
// A[M,K] (lda), B[N,K] (ldb). z = (zo<<L)|zi -> operand offsets zo*s?0+zi*s?1.
// EPI 3: merged QKV epilogue (sections q/k straight+bias, v transposed+bias).
// EPI 5: fp32 atomicAdd into Cv (split-K out-projection).
// EPI 6: scores: P' = bf16(exp(alpha*s - 4)) to Cv; row-sums atomicAdd to C2.
// EPI 7: PV: bf16(acc / l[row]) to Cv; l read from C2.
template <int EPI>
__global__ __launch_bounds__(512, 2) void gemm_nt(
    const us* __restrict__ A, int lda, long long sA0, long long sA1,
    const us* __restrict__ Bm, int ldb, long long sB0, long long sB1,
    const float* __restrict__ bias, const float* __restrict__ bias2,
    const float* __restrict__ bias3,
    void* __restrict__ Cv, void* __restrict__ C2, void* __restrict__ C3,
    int ldc, long long sC0, long long sC1,
    int K, float alpha, int L, int sbits) {
  // Fragment-linear: sub-tile s = mb*2+ks (mb = 16-row block, ks = k-half of
  // BK=64); chunk = s*64 + lane; chunk holds A[mb*16 + (lane&15)]
  // [ks*32 + (lane>>4)*8 .. +7]. 2048 chunks * 16 B = 32 KB per operand/buf.
  __shared__ __align__(16) us As[2][16384];
  __shared__ __align__(16) us Bs[2][16384];
  const int t = threadIdx.x;
  const int wv = t >> 6, ln = t & 63;
  const int m16 = ln & 15, quad = ln >> 4;

  // XCD-aware swizzle: flat%8 -> XCD. Remap so each XCD owns a contiguous
  // nid range -> operand slices stay L2-resident.
  const int gx = gridDim.x, gxy = gx * gridDim.y;
  const int nblk = gxy * gridDim.z;
  const int flat = blockIdx.x + gx * blockIdx.y + gxy * blockIdx.z;
  int nid = flat;
  if ((nblk & 7) == 0) nid = (flat & 7) * (nblk >> 3) + (flat >> 3);
  const int bz = nid / gxy, rem = nid % gxy;
  const int by = rem / gx, bx = rem % gx;

  const long long row0 = (long long)by * 256;
  const long long col0 = (long long)bx * 256;
  const int zo = bz >> L, zi = bz & ((1 << L) - 1);
  const us* Az = A + zo * sA0 + zi * sA1;
  const us* Bz = Bm + zo * sB0 + zi * sB1;

  // Staging: 2048 chunks per operand per K-tile; thread t stages chunks
  // c = t + 512*j (j=0..3), 16 B each, LDS dest linear at chunk*16.
  // A-load j covers rows [64j, 64j+63] of the tile.
  int offA[4], offB[4];
#pragma unroll
  for (int j = 0; j < 4; ++j) {
    const int c = t + 512 * j;
    const int s = c >> 6, l = c & 63;
    const int mb = s >> 1, ks = s & 1, qd = (l >> 4) & 3, mm = l & 15;
    offA[j] = (int)((row0 + mb * 16 + mm) * (long long)lda + ks * 32 + qd * 8);
    offB[j] = (int)((col0 + mb * 16 + mm) * (long long)ldb + ks * 32 + qd * 8);
  }

  f4v acc[8][4];
#pragma unroll
  for (int r = 0; r < 8; ++r)
#pragma unroll
    for (int c = 0; c < 4; ++c) acc[r][c] = (f4v){0.f, 0.f, 0.f, 0.f};

  const int nk = K >> 6;                // K-tiles of 64
  const int wr = wv >> 2, wc = wv & 3;  // wave -> 128-row / 64-col group

#define BARR __builtin_amdgcn_s_barrier()
#define LGKM0                                              \
  do {                                                     \
    asm volatile("s_waitcnt lgkmcnt(0)" ::: "memory");     \
    __builtin_amdgcn_sched_barrier(0);                     \
  } while (0)
#define READ_A(p_)                                                           \
  _Pragma("unroll") for (int rr = 0; rr < 2; ++rr)                           \
  _Pragma("unroll") for (int ks = 0; ks < 2; ++ks)                           \
      af[rr * 2 + ks] = *(const s8v*)&As[b]                                  \
          [(((wr * 8 + (p_) * 2 + rr) * 2 + ks) * 64 + ln) * 8];
#define MFMA_Q(p_)                                                           \
  __builtin_amdgcn_s_setprio(1);                                             \
  _Pragma("unroll") for (int ks = 0; ks < 2; ++ks)                           \
  _Pragma("unroll") for (int rr = 0; rr < 2; ++rr)                           \
  _Pragma("unroll") for (int c = 0; c < 4; ++c)                              \
      acc[(p_) * 2 + rr][c] = __builtin_amdgcn_mfma_f32_16x16x32_bf16(       \
          af[rr * 2 + ks], bfr[c * 2 + ks], acc[(p_) * 2 + rr][c], 0, 0, 0); \
  __builtin_amdgcn_s_setprio(0);

  // Prologue: tile 0 fully (8 loads) + tile 1's first 6 (B x4, A j0,j2).
  // vmcnt(6) drains tile 0's 8 (oldest); tile 1's 6 stay in flight.
#pragma unroll
  for (int j = 0; j < 4; ++j) gld16(Az + offA[j], (us*)As[0] + (t + 512 * j) * 8);
#pragma unroll
  for (int j = 0; j < 4; ++j) gld16(Bz + offB[j], (us*)Bs[0] + (t + 512 * j) * 8);
  if (nk > 1) {
#pragma unroll
    for (int j = 0; j < 4; ++j)
      gld16(Bz + offB[j] + 64, (us*)Bs[1] + (t + 512 * j) * 8);
    gld16(Az + offA[0] + 64, (us*)As[1] + t * 8);
    gld16(Az + offA[2] + 64, (us*)As[1] + (t + 1024) * 8);
    asm volatile("s_waitcnt vmcnt(6)" ::: "memory");
  } else {
    asm volatile("s_waitcnt vmcnt(0)" ::: "memory");
  }
  BARR;

  for (int kt = 0; kt < nk; ++kt) {
    const int b = kt & 1;
    s8v bfr[8], af[4];
    // ---- phase 0: B(all) + A(q0) reads; finish staging tile kt+1 (A j1,j3
    //      -> buf b^1: rows 64-127/192-255, retired since kt-1's phase 3).
#pragma unroll
    for (int c = 0; c < 4; ++c)
#pragma unroll
      for (int ks = 0; ks < 2; ++ks)
        bfr[c * 2 + ks] =
            *(const s8v*)&Bs[b][(((wc * 4 + c) * 2 + ks) * 64 + ln) * 8];
    READ_A(0);
    if (kt + 1 < nk) {
      const int kof = (kt + 1) << 6;
      gld16(Az + offA[1] + kof, (us*)As[b ^ 1] + (t + 512) * 8);
      gld16(Az + offA[3] + kof, (us*)As[b ^ 1] + (t + 1536) * 8);
    }
    asm volatile("s_waitcnt lgkmcnt(8)" ::: "memory");  // partial drain (12 reads)
    BARR; LGKM0; MFMA_Q(0); BARR;
    // ---- phase 1: A(q1); stage B(kt+2) -> buf b (B retired at phase-0 bar).
    READ_A(1);
    if (kt + 2 < nk) {
      const int kof = (kt + 2) << 6;
#pragma unroll
      for (int j = 0; j < 4; ++j)
        gld16(Bz + offB[j] + kof, (us*)Bs[b] + (t + 512 * j) * 8);
    }
    BARR; LGKM0; MFMA_Q(1); BARR;
    // ---- phase 2: A(q2); stage A(kt+2) j0,j2 -> buf b (rows 0-63/128-191,
    //      retired at phase-1 bar).
    READ_A(2);
    if (kt + 2 < nk) {
      const int kof = (kt + 2) << 6;
      gld16(Az + offA[0] + kof, (us*)As[b] + t * 8);
      gld16(Az + offA[2] + kof, (us*)As[b] + (t + 1024) * 8);
    }
    BARR; LGKM0; MFMA_Q(2); BARR;
    // ---- phase 3: A(q3); counted vmcnt at tile boundary: kt+2's 6 loads
    //      stay in flight; kt+1's 8 (oldest) drained.
    READ_A(3);
    BARR; LGKM0; MFMA_Q(3);
    if (kt + 2 < nk) asm volatile("s_waitcnt vmcnt(6)" ::: "memory");
    else             asm volatile("s_waitcnt vmcnt(0)" ::: "memory");
    BARR;
  }
#undef READ_A
#undef MFMA_Q
#undef BARR
#undef LGKM0

  // Epilogue. C/D layout: col = lane&15, row = quad*4 + reg (m89-verified).
  if (EPI == 6) {  // P' = exp(alpha*s - 4)
#pragma unroll
    for (int r = 0; r < 8; ++r)
#pragma unroll
      for (int c = 0; c < 4; ++c)
#pragma unroll
        for (int g = 0; g < 4; ++g)
          acc[r][c][g] = __expf(fmaf(acc[r][c][g], alpha, -4.f));
  }
#pragma unroll
  for (int r = 0; r < 8; ++r) {
    const int inRow = wr * 128 + r * 16 + quad * 4;
    const long long gr0 = row0 + inRow;
#pragma unroll
    for (int c = 0; c < 4; ++c) {
      const long long gc = col0 + wc * 64 + c * 16 + m16;
      if (EPI == 3) {
        // sections of HC*512 cols each: 0=q, 1=k, 2=v(transposed)
        const int which = (int)(gc >> sbits);
        const int gsec = (int)gc & ((1 << sbits) - 1);
        const int hc = gsec >> 9, e = (int)gc & 511;
        const long long slice =
            ((long long)zo * (1 << (sbits - 9)) + hc) * 1048576LL;  // S*E
        if (which == 0) {
          us* C = (us*)Cv;
          const float bb = bias[gsec];
#pragma unroll
          for (int g = 0; g < 4; ++g)
            C[slice + (gr0 + g) * 512 + e] = f2b(acc[r][c][g] + bb);
        } else if (which == 1) {
          us* C = (us*)C2;
          const float bb = bias2[gsec];
#pragma unroll
          for (int g = 0; g < 4; ++g)
            C[slice + (gr0 + g) * 512 + e] = f2b(acc[r][c][g] + bb);
        } else {
          us* C = (us*)C3;
          const float bb = bias3[gsec];
          us4v pk;
#pragma unroll
          for (int g = 0; g < 4; ++g) pk[g] = f2b(acc[r][c][g] + bb);
          *(us4v*)&C[slice + (long long)e * 2048 + gr0] = pk;  // e*S + s
        }
      } else if (EPI == 5) {  // split-K atomic accumulate (fp32)
        float* C = (float*)Cv + zo * sC0;
        float* p = C + gr0 * ldc + gc;
#pragma unroll
        for (int g = 0; g < 4; ++g)
          atomicAdd(&p[(long long)g * ldc], acc[r][c][g] * alpha);
      } else if (EPI == 6) {  // store P' bf16
        us* C = (us*)Cv + zo * sC0 + zi * sC1;
#pragma unroll
        for (int g = 0; g < 4; ++g)
          C[(gr0 + g) * (long long)ldc + gc] = f2b(acc[r][c][g]);
      } else {  // EPI 7: PV, scale by 1/l[row]
        us* C = (us*)Cv + zo * sC0 + zi * sC1;
        const float* lrow = (const float*)C2 + (long long)bz * 2048;
#pragma unroll
        for (int g = 0; g < 4; ++g) {
          const float inv = 1.f / lrow[gr0 + g];
          C[(gr0 + g) * (long long)ldc + gc] = f2b(acc[r][c][g] * inv);
        }
      }
    }
    if (EPI == 6) {  // row-sum partials over this wave's 64 cols
      float* lsum = (float*)C2 + (long long)bz * 2048;
#pragma unroll
      for (int g = 0; g < 4; ++g) {
        float s = acc[r][0][g] + acc[r][1][g] + acc[r][2][g] + acc[r][3][g];
        s += __shfl_xor(s, 1, 64);
        s += __shfl_xor(s, 2, 64);
        s += __shfl_xor(s, 4, 64);
        s += __shfl_xor(s, 8, 64);
        if (m16 == 0) atomicAdd(&lsum[gr0 + g], s);
      }
    }
  }
}

__global__ __launch_bounds__(256) void conv_bf16(const float* __restrict__ in,
                                                 us* __restrict__ out, int n4) {
  const int i = blockIdx.x * 256 + threadIdx.x;
  if (i < n4) {
    const float4 f = ((const float4*)in)[i];
    us4v o;
    o[0] = f2b(f.x); o[1] = f2b(f.y); o[2] = f2b(f.z); o[3] = f2b(f.w);
    ((us4v*)out)[i] = o;
  }
}

// in [Z][R][C] fp32 -> bf16 transposed [C][R], z-routed:
// dst = out + (z>>Lc)*sChunk + (z&mask)*(R*C)
__global__ __launch_bounds__(256) void conv_transpose(const float* __restrict__ in,
                                                      us* __restrict__ out,
                                                      int R, int C, int Lc,
                                                      int mask, long long sChunk) {
  __shared__ float tile[32][33];
  const int tx = threadIdx.x & 31, ty = threadIdx.x >> 5;
  const int z = blockIdx.z;
  const long long zi = (long long)z * R * C;
  us* dst = out + (long long)(z >> Lc) * sChunk + (long long)(z & mask) * R * C;
  const int r0 = blockIdx.y * 32, c0 = blockIdx.x * 32;
#pragma unroll
  for (int j = 0; j < 4; ++j)
    tile[ty + 8 * j][tx] = in[zi + (long long)(r0 + ty + 8 * j) * C + c0 + tx];
  __syncthreads();
#pragma unroll
  for (int j = 0; j < 4; ++j)
    dst[(long long)(c0 + ty + 8 * j) * R + r0 + tx] = f2b(tile[tx][ty + 8 * j]);
}

// out[b,s,:] = bp[:]; also zeroes the l (row-sum) region.
__global__ __launch_bounds__(256) void init_out_kernel(float* __restrict__ out,
                                                       const float* __restrict__ bp,
                                                       int total,
                                                       float* __restrict__ lz,
                                                       int lcnt) {
  const int i = blockIdx.x * 256 + threadIdx.x;
  if (i < total) out[i] = bp[i & 511];  // D=512
  else if (i < total + lcnt) lz[i - total] = 0.f;
}

extern "C" void kernel_launch(void* const* d_in, const int* in_sizes, int n_in,
                              void* d_out, int out_size, void* d_ws, size_t ws_size,
                              hipStream_t stream) {
  constexpr int Bb = 4, S = 2048, D = 512, H = 8, E = 512, HE = 4096;
  const float* x  = (const float*)d_in[0];
  const float* Wq = (const float*)d_in[1];
  const float* bq = (const float*)d_in[2];
  const float* Wk = (const float*)d_in[3];
  const float* bk = (const float*)d_in[4];
  const float* Wv = (const float*)d_in[5];
  const float* bv = (const float*)d_in[6];
  const float* Wp = (const float*)d_in[7];
  const float* bp = (const float*)d_in[8];
  float* out = (float*)d_out;

  const long long SE = (long long)S * E, SS = (long long)S * S;
  const long long SD = (long long)S * D, ED = (long long)E * D;

  // Fixed region: xh + packed QKV weights W3 + WpT (25.2 MB).
  us* xh  = (us*)d_ws;            // B*S*D          4,194,304
  us* W3  = xh + 4194304;         // [chunk][3][HC*E][D]  6,291,456 total
  us* WpT = W3 + 6291456;         // [D][HE]        2,097,152
  us* dyn = WpT + 2097152;

  // Head-chunk size. oh aliases qh (dead after scores GEMM).
  const size_t fixedB = (size_t)(4194304 + 6291456 + 2097152) * 2;
  const size_t lB = (size_t)H * Bb * S * 4;  // all chunks' row-sum buffers
  int HC = 8;
  while (HC > 1) {
    const size_t need = fixedB + lB +
        (size_t)HC * (3 * (size_t)Bb * SE + (size_t)Bb * SS) * 2;
    if (need <= ws_size) break;
    HC >>= 1;
  }
  const int Lh = (HC == 8) ? 3 : (HC == 4) ? 2 : (HC == 2) ? 1 : 0;
  const int BHC = Bb * HC;
  const int sbits = 9 + Lh;  // QKV section size = HC*512 cols

  us* qh = dyn;                       // [b*HC+hc][S][E]
  us* kh = qh + (size_t)BHC * SE;
  us* vT = kh + (size_t)BHC * SE;     // [b*HC+hc][E][S]
  us* sc = vT + (size_t)BHC * SE;     // [b*HC+hc][S][S]  (P' = exp(as-4))
  float* lb = (float*)(sc + (size_t)BHC * SS);  // [H*Bb][S] row sums
  us* oh = qh;                        // alias: [b][S][HC][E]

  const dim3 tb(256), tg(512);
  const int lcnt = H * Bb * S;
  init_out_kernel<<<dim3((Bb * S * D + lcnt + 255) / 256), tb, 0, stream>>>(
      out, bp, Bb * S * D, lb, lcnt);
  conv_bf16<<<dim3(4194304 / 4 / 256), tb, 0, stream>>>(x, xh, 4194304 / 4);
  const long long sChunk = 3LL * HC * ED;  // per-chunk W3 stride
  conv_transpose<<<dim3(16, 16, H), tb, 0, stream>>>(Wq, W3, D, E, Lh, HC - 1, sChunk);
  conv_transpose<<<dim3(16, 16, H), tb, 0, stream>>>(Wk, W3 + HC * ED, D, E, Lh, HC - 1, sChunk);
  conv_transpose<<<dim3(16, 16, H), tb, 0, stream>>>(Wv, W3 + 2 * HC * ED, D, E, Lh, HC - 1, sChunk);
  conv_transpose<<<dim3(16, 128, 1), tb, 0, stream>>>(Wp, WpT, HE, D, 0, 0, 0);

  const float aS = 0.044194173824159216f;  // 1/sqrt(512)
  const dim3 gQKV(3 * HC * E / 256, 8, Bb);    // 256-col tiles; S/256 = 8 rows
  const dim3 gS(8, 8, BHC);                    // 2048/256 cols
  const dim3 gPV(2, 8, BHC);                   // 512/256 cols
  const dim3 gOP(2, 8, BHC);                   // split-K: z = (b, j)

  for (int c = 0; c < H / HC; ++c) {
    const int h0 = c * HC;
    float* lc = lb + (long long)c * BHC * S;
    // Merged QKV projection: [S,D] @ [3*HC*E, D]^T; epilogue routes sections.
    gemm_nt<3><<<gQKV, tg, 0, stream>>>(
        xh, D, SD, 0, W3 + c * sChunk, D, 0, 0,
        bq + h0 * E, bk + h0 * E, bv + h0 * E,
        qh, kh, vT, 512, 0, SE, D, 1.f, 0, sbits);
    // P' = exp((Q K^T)/sqrt(E) - 4) -> bf16 [z][S][S]; row sums -> lc
    gemm_nt<6><<<gS, tg, 0, stream>>>(
        qh, E, (long long)HC * SE, SE, kh, E, (long long)HC * SE, SE,
        nullptr, nullptr, nullptr, sc, lc, nullptr,
        S, (long long)HC * SS, SS, E, aS, Lh, 0);
    // O = (P' @ V) / l  -> oh [b][S][HC][E]
    gemm_nt<7><<<gPV, tg, 0, stream>>>(
        sc, S, (long long)HC * SS, SS, vT, S, (long long)HC * SE, SE,
        nullptr, nullptr, nullptr, oh, lc, nullptr,
        HC * E, (long long)S * HC * E, E, S, 1.f, Lh, 0);
    // out += O @ Wp-chunk, split-K: z=(b, j), K=512 per split, atomicAdd.
    gemm_nt<5><<<gOP, tg, 0, stream>>>(
        oh, HC * E, (long long)S * HC * E, 512,
        WpT + (long long)h0 * E, HE, 0, 512,
        nullptr, nullptr, nullptr, out, nullptr, nullptr,
        D, SD, 0, 512, 1.f, Lh, 0);
  }
}

// Round 12
// 911.849 us; speedup vs baseline: 2.4662x; 1.0255x over previous
//
#include <hip/hip_runtime.h>

// R19: occupancy-at-constant-intensity test. All R8-R15 staged GEMMs run at
// ~430-530 TF = ~3.3 TB/s LDS-staging rate; the only faster stager (R8,
// 4.6 TB/s) was the only one with >=2 blocks/CU, but its smaller tile had
// lower intensity. R19 keeps the 256x256 tile (131 FLOP/staged-byte) and
// halves BK to 32 -> LDS 64 KB -> 2 blocks/CU. K-loop: 2 phases x 16 MFMA
// per 32-K tile; sub-tile slots bit-swap-permuted so load-half j0 = ph0
// retirement set, j1 = ph1 set; stages interleaved into phases (R10 idiom);
// counted vmcnt(3) once per K-tile; setprio around MFMA. Epilogues, K
// accumulation order, host pipeline identical to R18 (absmax unchanged).

typedef short s8v __attribute__((ext_vector_type(8)));   // 8 bf16 = 4 VGPRs
typedef float f4v __attribute__((ext_vector_type(4)));
typedef unsigned short us;
typedef us us4v __attribute__((ext_vector_type(4)));

__device__ inline us f2b(float f) {  // fp32 -> bf16 RNE
  union { float f; unsigned u; } v; v.f = f;
  unsigned r = v.u + 0x7FFFu + ((v.u >> 16) & 1u);
  return (us)(r >> 16);
}

// async global->LDS, 16 B per lane; LDS dest = wave-uniform base + lane*16.
__device__ inline void gld16(const us* g, us* l) {
  __builtin_amdgcn_global_load_lds(
      (const __attribute__((address_space(1))) void*)g,
      (__attribute__((address_space(3))) void*)l, 16, 0, 0);
}

// Sub-tile slot permutation (involution, bit2<->bit3): slots 0..7 (load j0)
// hold sub-tiles {0,1,2,3,8,9,10,11} = the ph0 read set for both wave rows;
// slots 8..15 (j1) hold {4,5,6,7,12,13,14,15} = ph1 set. So A j0 retires at
// ph0's post-MFMA barrier, A j1 at ph1's.
#define PERM(s_) (((s_) & 3) | (((s_) & 4) << 1) | (((s_) & 8) >> 1))

// NT GEMM core: 256(M) x 256(N) tile, BK=32, 8 waves (2 row x 4 col groups);
// A[M,K] (lda), B[N,K] (ldb). z = (zo<<L)|zi -> operand offsets zo*s?0+zi*s?1.
// EPI 3: merged QKV epilogue (sections q/k straight+bias, v transposed+bias).
// EPI 5: fp32 atomicAdd into Cv (split-K out-projection).
// EPI 6: scores: P' = bf16(exp(alpha*s - 4)) to Cv; row-sums atomicAdd to C2.
// EPI 7: PV: bf16(acc / l[row]) to Cv; l read from C2.
template <int EPI>
__global__ __launch_bounds__(512, 2) void gemm_nt(
    const us* __restrict__ A, int lda, long long sA0, long long sA1,
    const us* __restrict__ Bm, int ldb, long long sB0, long long sB1,
    const float* __restrict__ bias, const float* __restrict__ bias2,
    const float* __restrict__ bias3,
    void* __restrict__ Cv, void* __restrict__ C2, void* __restrict__ C3,
    int ldc, long long sC0, long long sC1,
    int K, float alpha, int L, int sbits) {
  // Fragment-linear, BK=32: slot s in [0,16), chunk = s*64 + lane; chunk
  // holds A[PERM(s)*16 + (lane&15)][(lane>>4)*8 .. +7] of the K-tile.
  // 1024 chunks * 16 B = 16 KB per operand per buffer -> 64 KB total.
  __shared__ __align__(16) us As[2][8192];
  __shared__ __align__(16) us Bs[2][8192];
  const int t = threadIdx.x;
  const int wv = t >> 6, ln = t & 63;
  const int m16 = ln & 15, quad = ln >> 4;

  // XCD-aware swizzle: flat%8 -> XCD. Remap so each XCD owns a contiguous
  // nid range -> operand slices stay L2-resident.
  const int gx = gridDim.x, gxy = gx * gridDim.y;
  const int nblk = gxy * gridDim.z;
  const int flat = blockIdx.x + gx * blockIdx.y + gxy * blockIdx.z;
  int nid = flat;
  if ((nblk & 7) == 0) nid = (flat & 7) * (nblk >> 3) + (flat >> 3);
  const int bz = nid / gxy, rem = nid % gxy;
  const int by = rem / gx, bx = rem % gx;

  const long long row0 = (long long)by * 256;
  const long long col0 = (long long)bx * 256;
  const int zo = bz >> L, zi = bz & ((1 << L) - 1);
  const us* Az = A + zo * sA0 + zi * sA1;
  const us* Bz = Bm + zo * sB0 + zi * sB1;

  // Staging: thread t stages chunks c = t + 512*j (j=0,1), 16 B each, LDS
  // dest linear at chunk*16; global source row uses PERM(slot).
  int offA[2], offB[2];
#pragma unroll
  for (int j = 0; j < 2; ++j) {
    const int c = t + 512 * j;
    const int s = c >> 6;
    const int sp = PERM(s);
    const int mm = c & 15, qd = (c >> 4) & 3;
    offA[j] = (int)((row0 + sp * 16 + mm) * (long long)lda + qd * 8);
    offB[j] = (int)((col0 + sp * 16 + mm) * (long long)ldb + qd * 8);
  }

  f4v acc[8][4];
#pragma unroll
  for (int r = 0; r < 8; ++r)
#pragma unroll
    for (int c = 0; c < 4; ++c) acc[r][c] = (f4v){0.f, 0.f, 0.f, 0.f};

  const int nk = K >> 5;                // K-tiles of 32
  const int wr = wv >> 2, wc = wv & 3;  // wave -> 128-row / 64-col group

#define BARR __builtin_amdgcn_s_barrier()
#define LGKM0                                              \
  do {                                                     \
    asm volatile("s_waitcnt lgkmcnt(0)" ::: "memory");     \
    __builtin_amdgcn_sched_barrier(0);                     \
  } while (0)
#define MFMA16(r0_)                                                          \
  __builtin_amdgcn_s_setprio(1);                                             \
  _Pragma("unroll") for (int rr = 0; rr < 4; ++rr)                           \
  _Pragma("unroll") for (int cc = 0; cc < 4; ++cc)                           \
      acc[(r0_) + rr][cc] = __builtin_amdgcn_mfma_f32_16x16x32_bf16(         \
          af[rr], bfr[cc], acc[(r0_) + rr][cc], 0, 0, 0);                    \
  __builtin_amdgcn_s_setprio(0);

  // Prologue: tile 0 fully (4 loads) + tile 1's first 3 (B j0,j1, A j0).
  // vmcnt(3) drains tile 0's 4 (oldest); tile 1's 3 stay in flight.
  gld16(Bz + offB[0], (us*)Bs[0] + t * 8);
  gld16(Bz + offB[1], (us*)Bs[0] + (t + 512) * 8);
  gld16(Az + offA[0], (us*)As[0] + t * 8);
  gld16(Az + offA[1], (us*)As[0] + (t + 512) * 8);
  if (nk > 1) {
    gld16(Bz + offB[0] + 32, (us*)Bs[1] + t * 8);
    gld16(Bz + offB[1] + 32, (us*)Bs[1] + (t + 512) * 8);
    gld16(Az + offA[0] + 32, (us*)As[1] + t * 8);
    asm volatile("s_waitcnt vmcnt(3)" ::: "memory");
  } else {
    asm volatile("s_waitcnt vmcnt(0)" ::: "memory");
  }
  BARR;

  for (int kt = 0; kt < nk; ++kt) {
    const int b = kt & 1;
    s8v bfr[4], af[4];
    // ---- phase 0: all B-frags + A sub-tiles {wr*8+0..3}; finish staging
    //      tile kt+1 (A j1 -> As[b^1] ph1-region, retired at kt-1's ph1 bar).
#pragma unroll
    for (int cc = 0; cc < 4; ++cc)
      bfr[cc] = *(const s8v*)&Bs[b][(PERM(wc * 4 + cc) * 64 + ln) * 8];
#pragma unroll
    for (int rr = 0; rr < 4; ++rr)
      af[rr] = *(const s8v*)&As[b][(PERM(wr * 8 + rr) * 64 + ln) * 8];
    if (kt + 1 < nk)
      gld16(Az + offA[1] + ((kt + 1) << 5), (us*)As[b ^ 1] + (t + 512) * 8);
    BARR; LGKM0; MFMA16(0); BARR;
    // ---- phase 1: A sub-tiles {wr*8+4..7}; stage tile kt+2's B j0,j1 and
    //      A j0 -> buf b (B + A-ph0-region retired at phase-0's post bar).
#pragma unroll
    for (int rr = 0; rr < 4; ++rr)
      af[rr] = *(const s8v*)&As[b][(PERM(wr * 8 + 4 + rr) * 64 + ln) * 8];
    if (kt + 2 < nk) {
      const int kof = (kt + 2) << 5;
      gld16(Bz + offB[0] + kof, (us*)Bs[b] + t * 8);
      gld16(Bz + offB[1] + kof, (us*)Bs[b] + (t + 512) * 8);
      gld16(Az + offA[0] + kof, (us*)As[b] + t * 8);
    }
    BARR; LGKM0; MFMA16(4);
    // Tile boundary: kt+2's 3 loads stay in flight; kt+1's (oldest) drained.
    if (kt + 2 < nk) asm volatile("s_waitcnt vmcnt(3)" ::: "memory");
    else             asm volatile("s_waitcnt vmcnt(0)" ::: "memory");
    BARR;
  }
#undef MFMA16
#undef BARR
#undef LGKM0

  // Epilogue. C/D layout: col = lane&15, row = quad*4 + reg (m89-verified).
  if (EPI == 6) {  // P' = exp(alpha*s - 4)
#pragma unroll
    for (int r = 0; r < 8; ++r)
#pragma unroll
      for (int c = 0; c < 4; ++c)
#pragma unroll
        for (int g = 0; g < 4; ++g)
          acc[r][c][g] = __expf(fmaf(acc[r][c][g], alpha, -4.f));
  }
#pragma unroll
  for (int r = 0; r < 8; ++r) {
    const int inRow = wr * 128 + r * 16 + quad * 4;
    const long long gr0 = row0 + inRow;
#pragma unroll
    for (int c = 0; c < 4; ++c) {
      const long long gc = col0 + wc * 64 + c * 16 + m16;
      if (EPI == 3) {
        // sections of HC*512 cols each: 0=q, 1=k, 2=v(transposed)
        const int which = (int)(gc >> sbits);
        const int gsec = (int)gc & ((1 << sbits) - 1);
        const int hc = gsec >> 9, e = (int)gc & 511;
        const long long slice =
            ((long long)zo * (1 << (sbits - 9)) + hc) * 1048576LL;  // S*E
        if (which == 0) {
          us* C = (us*)Cv;
          const float bb = bias[gsec];
#pragma unroll
          for (int g = 0; g < 4; ++g)
            C[slice + (gr0 + g) * 512 + e] = f2b(acc[r][c][g] + bb);
        } else if (which == 1) {
          us* C = (us*)C2;
          const float bb = bias2[gsec];
#pragma unroll
          for (int g = 0; g < 4; ++g)
            C[slice + (gr0 + g) * 512 + e] = f2b(acc[r][c][g] + bb);
        } else {
          us* C = (us*)C3;
          const float bb = bias3[gsec];
          us4v pk;
#pragma unroll
          for (int g = 0; g < 4; ++g) pk[g] = f2b(acc[r][c][g] + bb);
          *(us4v*)&C[slice + (long long)e * 2048 + gr0] = pk;  // e*S + s
        }
      } else if (EPI == 5) {  // split-K atomic accumulate (fp32)
        float* C = (float*)Cv + zo * sC0;
        float* p = C + gr0 * ldc + gc;
#pragma unroll
        for (int g = 0; g < 4; ++g)
          atomicAdd(&p[(long long)g * ldc], acc[r][c][g] * alpha);
      } else if (EPI == 6) {  // store P' bf16
        us* C = (us*)Cv + zo * sC0 + zi * sC1;
#pragma unroll
        for (int g = 0; g < 4; ++g)
          C[(gr0 + g) * (long long)ldc + gc] = f2b(acc[r][c][g]);
      } else {  // EPI 7: PV, scale by 1/l[row]
        us* C = (us*)Cv + zo * sC0 + zi * sC1;
        const float* lrow = (const float*)C2 + (long long)bz * 2048;
#pragma unroll
        for (int g = 0; g < 4; ++g) {
          const float inv = 1.f / lrow[gr0 + g];
          C[(gr0 + g) * (long long)ldc + gc] = f2b(acc[r][c][g] * inv);
        }
      }
    }
    if (EPI == 6) {  // row-sum partials over this wave's 64 cols
      float* lsum = (float*)C2 + (long long)bz * 2048;
#pragma unroll
      for (int g = 0; g < 4; ++g) {
        float s = acc[r][0][g] + acc[r][1][g] + acc[r][2][g] + acc[r][3][g];
        s += __shfl_xor(s, 1, 64);
        s += __shfl_xor(s, 2, 64);
        s += __shfl_xor(s, 4, 64);
        s += __shfl_xor(s, 8, 64);
        if (m16 == 0) atomicAdd(&lsum[gr0 + g], s);
      }
    }
  }
}

__global__ __launch_bounds__(256) void conv_bf16(const float* __restrict__ in,
                                                 us* __restrict__ out, int n4) {
  const int i = blockIdx.x * 256 + threadIdx.x;
  if (i < n4) {
    const float4 f = ((const float4*)in)[i];
    us4v o;
    o[0] = f2b(f.x); o[1] = f2b(f.y); o[2] = f2b(f.z); o[3] = f2b(f.w);
    ((us4v*)out)[i] = o;
  }
}

// in [Z][R][C] fp32 -> bf16 transposed [C][R], z-routed:
// dst = out + (z>>Lc)*sChunk + (z&mask)*(R*C)
__global__ __launch_bounds__(256) void conv_transpose(const float* __restrict__ in,
                                                      us* __restrict__ out,
                                                      int R, int C, int Lc,
                                                      int mask, long long sChunk) {
  __shared__ float tile[32][33];
  const int tx = threadIdx.x & 31, ty = threadIdx.x >> 5;
  const int z = blockIdx.z;
  const long long zi = (long long)z * R * C;
  us* dst = out + (long long)(z >> Lc) * sChunk + (long long)(z & mask) * R * C;
  const int r0 = blockIdx.y * 32, c0 = blockIdx.x * 32;
#pragma unroll
  for (int j = 0; j < 4; ++j)
    tile[ty + 8 * j][tx] = in[zi + (long long)(r0 + ty + 8 * j) * C + c0 + tx];
  __syncthreads();
#pragma unroll
  for (int j = 0; j < 4; ++j)
    dst[(long long)(c0 + ty + 8 * j) * R + r0 + tx] = f2b(tile[tx][ty + 8 * j]);
}

// out[b,s,:] = bp[:]; also zeroes the l (row-sum) region.
__global__ __launch_bounds__(256) void init_out_kernel(float* __restrict__ out,
                                                       const float* __restrict__ bp,
                                                       int total,
                                                       float* __restrict__ lz,
                                                       int lcnt) {
  const int i = blockIdx.x * 256 + threadIdx.x;
  if (i < total) out[i] = bp[i & 511];  // D=512
  else if (i < total + lcnt) lz[i - total] = 0.f;
}

extern "C" void kernel_launch(void* const* d_in, const int* in_sizes, int n_in,
                              void* d_out, int out_size, void* d_ws, size_t ws_size,
                              hipStream_t stream) {
  constexpr int Bb = 4, S = 2048, D = 512, H = 8, E = 512, HE = 4096;
  const float* x  = (const float*)d_in[0];
  const float* Wq = (const float*)d_in[1];
  const float* bq = (const float*)d_in[2];
  const float* Wk = (const float*)d_in[3];
  const float* bk = (const float*)d_in[4];
  const float* Wv = (const float*)d_in[5];
  const float* bv = (const float*)d_in[6];
  const float* Wp = (const float*)d_in[7];
  const float* bp = (const float*)d_in[8];
  float* out = (float*)d_out;

  const long long SE = (long long)S * E, SS = (long long)S * S;
  const long long SD = (long long)S * D, ED = (long long)E * D;

  // Fixed region: xh + packed QKV weights W3 + WpT (25.2 MB).
  us* xh  = (us*)d_ws;            // B*S*D          4,194,304
  us* W3  = xh + 4194304;         // [chunk][3][HC*E][D]  6,291,456 total
  us* WpT = W3 + 6291456;         // [D][HE]        2,097,152
  us* dyn = WpT + 2097152;

  // Head-chunk size. oh aliases qh (dead after scores GEMM).
  const size_t fixedB = (size_t)(4194304 + 6291456 + 2097152) * 2;
  const size_t lB = (size_t)H * Bb * S * 4;  // all chunks' row-sum buffers
  int HC = 8;
  while (HC > 1) {
    const size_t need = fixedB + lB +
        (size_t)HC * (3 * (size_t)Bb * SE + (size_t)Bb * SS) * 2;
    if (need <= ws_size) break;
    HC >>= 1;
  }
  const int Lh = (HC == 8) ? 3 : (HC == 4) ? 2 : (HC == 2) ? 1 : 0;
  const int BHC = Bb * HC;
  const int sbits = 9 + Lh;  // QKV section size = HC*512 cols

  us* qh = dyn;                       // [b*HC+hc][S][E]
  us* kh = qh + (size_t)BHC * SE;
  us* vT = kh + (size_t)BHC * SE;     // [b*HC+hc][E][S]
  us* sc = vT + (size_t)BHC * SE;     // [b*HC+hc][S][S]  (P' = exp(as-4))
  float* lb = (float*)(sc + (size_t)BHC * SS);  // [H*Bb][S] row sums
  us* oh = qh;                        // alias: [b][S][HC][E]

  const dim3 tb(256), tg(512);
  const int lcnt = H * Bb * S;
  init_out_kernel<<<dim3((Bb * S * D + lcnt + 255) / 256), tb, 0, stream>>>(
      out, bp, Bb * S * D, lb, lcnt);
  conv_bf16<<<dim3(4194304 / 4 / 256), tb, 0, stream>>>(x, xh, 4194304 / 4);
  const long long sChunk = 3LL * HC * ED;  // per-chunk W3 stride
  conv_transpose<<<dim3(16, 16, H), tb, 0, stream>>>(Wq, W3, D, E, Lh, HC - 1, sChunk);
  conv_transpose<<<dim3(16, 16, H), tb, 0, stream>>>(Wk, W3 + HC * ED, D, E, Lh, HC - 1, sChunk);
  conv_transpose<<<dim3(16, 16, H), tb, 0, stream>>>(Wv, W3 + 2 * HC * ED, D, E, Lh, HC - 1, sChunk);
  conv_transpose<<<dim3(16, 128, 1), tb, 0, stream>>>(Wp, WpT, HE, D, 0, 0, 0);

  const float aS = 0.044194173824159216f;  // 1/sqrt(512)
  const dim3 gQKV(3 * HC * E / 256, 8, Bb);    // 256-col tiles; S/256 = 8 rows
  const dim3 gS(8, 8, BHC);                    // 2048/256 cols
  const dim3 gPV(2, 8, BHC);                   // 512/256 cols
  const dim3 gOP(2, 8, BHC);                   // split-K: z = (b, j)

  for (int c = 0; c < H / HC; ++c) {
    const int h0 = c * HC;
    float* lc = lb + (long long)c * BHC * S;
    // Merged QKV projection: [S,D] @ [3*HC*E, D]^T; epilogue routes sections.
    gemm_nt<3><<<gQKV, tg, 0, stream>>>(
        xh, D, SD, 0, W3 + c * sChunk, D, 0, 0,
        bq + h0 * E, bk + h0 * E, bv + h0 * E,
        qh, kh, vT, 512, 0, SE, D, 1.f, 0, sbits);
    // P' = exp((Q K^T)/sqrt(E) - 4) -> bf16 [z][S][S]; row sums -> lc
    gemm_nt<6><<<gS, tg, 0, stream>>>(
        qh, E, (long long)HC * SE, SE, kh, E, (long long)HC * SE, SE,
        nullptr, nullptr, nullptr, sc, lc, nullptr,
        S, (long long)HC * SS, SS, E, aS, Lh, 0);
    // O = (P' @ V) / l  -> oh [b][S][HC][E]
    gemm_nt<7><<<gPV, tg, 0, stream>>>(
        sc, S, (long long)HC * SS, SS, vT, S, (long long)HC * SE, SE,
        nullptr, nullptr, nullptr, oh, lc, nullptr,
        HC * E, (long long)S * HC * E, E, S, 1.f, Lh, 0);
    // out += O @ Wp-chunk, split-K: z=(b, j), K=512 per split, atomicAdd.
    gemm_nt<5><<<gOP, tg, 0, stream>>>(
        oh, HC * E, (long long)S * HC * E, 512,
        WpT + (long long)h0 * E, HE, 0, 512,
        nullptr, nullptr, nullptr, out, nullptr, nullptr,
        D, SD, 0, 512, 1.f, Lh, 0);
  }
}